// Round 3
// baseline (954.525 us; speedup 1.0000x reference)
//
#include <hip/hip_runtime.h>
#include <math.h>

#define BATCH 4096
#define HID   1024
#define KDIM  1024
#define NSTEP 15
#define KV    3072      // virtual K: [A_hi·B_hi | A_hi·B_lo | A_lo·B_hi]
#define NCHUNK (KV / 64)

// LDS-FREE MFMA GEMM: 64 threads = 1 wave per block; wave tile 64(M) x 64(N).
// Fragments gathered directly from global (16 rows x 64B = 16 cache lines per
// load = same line count as coalesced). No LDS, no barriers: the R0-R2 rounds
// proved the kernel was LDS-BW-bound (192KB/chunk/CU ~ 2500cyc); VMEM was idle.
// Depth-3 register pipeline (named sets, static indexing) covers L2 latency.

typedef _Float16 half8 __attribute__((ext_vector_type(8)));
typedef float floatx4 __attribute__((ext_vector_type(4)));

__device__ __forceinline__ _Float16 f16hi(float x) { return (_Float16)x; }

// B3[n][kv]: kv<1024: hi(W[n][kv]); 1024..2047: lo; 2048..3071: hi (dup).
// Also: split inputs/hidden into f16 hi/lo, init lists/accums.
__global__ __launch_bounds__(256) void setup_kernel(
    const float* __restrict__ W_ih, const float* __restrict__ W_hh,
    const float* __restrict__ inputs, const float* __restrict__ hidden,
    _Float16* __restrict__ B3ih, _Float16* __restrict__ B3hh,
    _Float16* __restrict__ Ihi, _Float16* __restrict__ Ilo,
    _Float16* __restrict__ Hhi, _Float16* __restrict__ Hlo,
    float* __restrict__ flagcol, int* __restrict__ list0, int* __restrict__ counts,
    float* __restrict__ halt_accum, float* __restrict__ tot_rem) {
    size_t idx = (size_t)blockIdx.x * 256 + threadIdx.x;   // grid 16384 -> 4M
    {   // split inputs -> I, hidden -> H
        float x = inputs[idx];
        _Float16 h = f16hi(x);
        Ihi[idx] = h; Ilo[idx] = (_Float16)(x - (float)h);
        float y = hidden[idx];
        _Float16 g = f16hi(y);
        Hhi[idx] = g; Hlo[idx] = (_Float16)(y - (float)g);
    }
    if (idx < (size_t)KDIM * KDIM) {
        int n = (int)(idx >> 10), k = (int)(idx & 1023);
        float w = W_hh[idx];
        _Float16 hi = f16hi(w);
        _Float16 lo = (_Float16)(w - (float)hi);
        size_t base = (size_t)n * KV;
        B3hh[base + k] = hi; B3hh[base + 1024 + k] = lo; B3hh[base + 2048 + k] = hi;
        float w2 = W_ih[(size_t)n * 1025 + k];
        _Float16 hi2 = f16hi(w2);
        _Float16 lo2 = (_Float16)(w2 - (float)hi2);
        B3ih[base + k] = hi2; B3ih[base + 1024 + k] = lo2; B3ih[base + 2048 + k] = hi2;
    }
    if (idx < BATCH) { list0[idx] = idx; halt_accum[idx] = 0.f; tot_rem[idx] = 0.f; }
    if (idx < KDIM) flagcol[idx] = W_ih[idx * 1025 + 1024];
    if (idx < 16) counts[idx] = (idx == 0) ? BATCH : 0;
}

// mode 0: xout[row] = A @ B^T + bias (fp32)
// mode 1: h = tanh(acc + xbase + flag*flagcol + bias); store h fp32 + hi/lo f16
// Grid: 1024 1-D blocks of 64 threads. id -> (bx = id>>4 over M, by = id&15
// over N): y-fastest so tail blocks (small bx) spread across XCDs, and the 4
// co-resident blocks per CU share the same B panel (L1 reuse x4).
__global__ __launch_bounds__(64, 1) void mfma_step_kernel(
    const _Float16* __restrict__ Ahi, const _Float16* __restrict__ Alo,
    const _Float16* __restrict__ B3, const float* __restrict__ bias,
    const float* __restrict__ xbase, const float* __restrict__ flagcol, float flag,
    const int* __restrict__ list, const int* __restrict__ pcount,
    float* __restrict__ hout, _Float16* __restrict__ houthi, _Float16* __restrict__ houtlo,
    float* __restrict__ xout, int mode) {
    int count = pcount ? *pcount : BATCH;
    int bx = blockIdx.x >> 4, by = blockIdx.x & 15;
    int row0 = bx * 64;
    if (row0 >= count) return;
    int col0 = by * 64;

    int lane = threadIdx.x;
    int l15 = lane & 15, l4 = lane >> 4;
    int koff = l4 * 8;               // k sub-offset within 32-wide half-chunk

    // Per-lane fragment base offsets (halfs). A rows gathered via list.
    size_t abase[4], bbase[4];
#pragma unroll
    for (int f = 0; f < 4; f++) {
        int grow = row0 + f * 16 + l15;
        int g = (grow < count) ? (list ? list[grow] : grow) : 0;
        abase[f] = (size_t)g * KDIM + koff;
        bbase[f] = (size_t)(col0 + f * 16 + l15) * KV + koff;
    }

    floatx4 acc[4][4];
#pragma unroll
    for (int i = 0; i < 4; i++)
#pragma unroll
        for (int j = 0; j < 4; j++) acc[i][j] = (floatx4)(0.f);

    // Three named register sets (static indexing only — rule #20).
    half8 avA[4][2], bvA[4][2];
    half8 avB[4][2], bvB[4][2];
    half8 avC[4][2], bvC[4][2];

#define ISSUE(av, bv, c) do {                                                 \
        int k0v_ = (c) << 6;                                                  \
        const _Float16* As_ = (k0v_ < 2048) ? Ahi : Alo; /* segs [hi,hi,lo] */ \
        int kp_ = k0v_ & 1023;                                                \
        _Pragma("unroll")                                                     \
        for (int f = 0; f < 4; f++) {                                         \
            _Pragma("unroll")                                                 \
            for (int ks = 0; ks < 2; ks++) {                                  \
                av[f][ks] = *(const half8*)(As_ + abase[f] + kp_ + ks * 32);  \
                bv[f][ks] = *(const half8*)(B3 + bbase[f] + k0v_ + ks * 32);  \
            }                                                                 \
        }                                                                     \
    } while (0)

#define MFMA_SET(av, bv) do {                                                 \
        _Pragma("unroll")                                                     \
        for (int ks = 0; ks < 2; ks++)                                        \
            _Pragma("unroll")                                                 \
            for (int fi = 0; fi < 4; fi++)                                    \
                _Pragma("unroll")                                             \
                for (int fj = 0; fj < 4; fj++)                                \
                    acc[fi][fj] = __builtin_amdgcn_mfma_f32_16x16x32_f16(     \
                        av[fi][ks], bv[fj][ks], acc[fi][fj], 0, 0, 0);        \
    } while (0)

    // prologue: chunks 0,1,2 in flight
    ISSUE(avA, bvA, 0);
    ISSUE(avB, bvB, 1);
    ISSUE(avC, bvC, 2);

    for (int it = 0; it < NCHUNK; it += 3) {
        MFMA_SET(avA, bvA);                         // chunk it
        if (it + 3 < NCHUNK) ISSUE(avA, bvA, it + 3);
        MFMA_SET(avB, bvB);                         // chunk it+1
        if (it + 4 < NCHUNK) ISSUE(avB, bvB, it + 4);
        MFMA_SET(avC, bvC);                         // chunk it+2
        if (it + 5 < NCHUNK) ISSUE(avC, bvC, it + 5);
    }

#undef ISSUE
#undef MFMA_SET

    // epilogue: C/D layout col = lane&15, row = (lane>>4)*4 + reg  [m89-verified]
#pragma unroll
    for (int fi = 0; fi < 4; fi++) {
#pragma unroll
        for (int rr = 0; rr < 4; rr++) {
            int lm = fi * 16 + l4 * 4 + rr;
            int grd = row0 + lm;
            if (grd >= count) continue;
            int g = list ? list[grd] : grd;
#pragma unroll
            for (int fj = 0; fj < 4; fj++) {
                int c = col0 + fj * 16 + l15;
                float v = acc[fi][fj][rr];
                if (mode == 0) {
                    xout[(size_t)g * KDIM + c] = v + bias[c];
                } else {
                    v += xbase[(size_t)g * KDIM + c] + flag * flagcol[c] + bias[c];
                    v = tanhf(v);
                    hout[(size_t)g * KDIM + c] = v;
                    _Float16 hi = f16hi(v);
                    houthi[(size_t)g * KDIM + c] = hi;
                    houtlo[(size_t)g * KDIM + c] = (_Float16)(v - (float)hi);
                }
            }
        }
    }
}

// One wave per active row: halt logit, sigmoid, halting state machine,
// tot_h accumulation into d_out, compaction of next-step list.  (R1-verified)
__global__ __launch_bounds__(256) void halt_kernel(
    const float* __restrict__ h, const float* __restrict__ W_halt,
    const float* __restrict__ b_halt,
    const int* __restrict__ list, const int* __restrict__ pcount,
    int* __restrict__ list_next, int* __restrict__ pcount_next,
    float* __restrict__ halt_accum, float* __restrict__ tot_rem,
    float* __restrict__ tot_h, float* __restrict__ steps_out,
    int stepnum, int first) {
    int count = *pcount;
    int wid = threadIdx.x >> 6, lane = threadIdx.x & 63;
    int r = blockIdx.x * 4 + wid;
    if (r >= count) return;
    int row = list[r];
    const float* hr = h + (size_t)row * HID;

    float dot = 0.f;
#pragma unroll
    for (int q = 0; q < 4; q++) {
        int c = q * 256 + lane * 4;
        float4 hv = *(const float4*)(hr + c);
        float4 wv = *(const float4*)(W_halt + c);
        dot += hv.x * wv.x + hv.y * wv.y + hv.z * wv.z + hv.w * wv.w;
    }
#pragma unroll
    for (int off = 32; off > 0; off >>= 1) dot += __shfl_down(dot, off);

    float combined = 0.f;
    if (lane == 0) {
        float p = 1.f / (1.f + expf(-(dot + b_halt[0])));
        float S = halt_accum[row] + p;
        halt_accum[row] = S;
        tot_rem[row] += p;
        bool ending = (S + p) > 0.99f;      // budget = 1 - PONDER_EPS
        if (ending) {
            combined = p + (1.f - S);
            steps_out[row] = (float)stepnum;
        } else {
            combined = p;
            int idx = atomicAdd(pcount_next, 1);
            list_next[idx] = row;
        }
    }
    combined = __shfl(combined, 0);

    float* th = tot_h + (size_t)row * HID;
#pragma unroll
    for (int q = 0; q < 4; q++) {
        int c = q * 256 + lane * 4;
        float4 hv = *(const float4*)(hr + c);
        float4 ov;
        if (first) {
            ov.x = combined * hv.x; ov.y = combined * hv.y;
            ov.z = combined * hv.z; ov.w = combined * hv.w;
        } else {
            ov = *(const float4*)(th + c);
            ov.x += combined * hv.x; ov.y += combined * hv.y;
            ov.z += combined * hv.z; ov.w += combined * hv.w;
        }
        *(float4*)(th + c) = ov;
    }
}

// blocks 0..1023: survivors get (1 - halt_accum) * h_final, steps = 16.
// block 1024: ponder reduction.
__global__ __launch_bounds__(256) void epilogue_kernel(
    const float* __restrict__ h, const int* __restrict__ list,
    const int* __restrict__ pcount, const float* __restrict__ halt_accum,
    const float* __restrict__ tot_rem,
    float* __restrict__ tot_h, float* __restrict__ steps_out,
    float* __restrict__ ponder) {
    if (blockIdx.x == 1024) {
        __shared__ float red[4];
        int t = threadIdx.x;
        float v = 0.f;
#pragma unroll
        for (int i = 0; i < 16; i++) v += tot_rem[t + i * 256];
#pragma unroll
        for (int off = 32; off > 0; off >>= 1) v += __shfl_down(v, off);
        int lane = t & 63, wid = t >> 6;
        if (lane == 0) red[wid] = v;
        __syncthreads();
        if (t == 0) ponder[0] = (red[0] + red[1] + red[2] + red[3]) * (-0.01f / 4096.f);
        return;
    }
    int count = *pcount;
    int wid = threadIdx.x >> 6, lane = threadIdx.x & 63;
    int r = blockIdx.x * 4 + wid;
    if (r >= count) return;
    int row = list[r];
    float cmb = 1.f - halt_accum[row];
    if (lane == 0) steps_out[row] = 16.f;
    const float* hr = h + (size_t)row * HID;
    float* th = tot_h + (size_t)row * HID;
#pragma unroll
    for (int q = 0; q < 4; q++) {
        int c = q * 256 + lane * 4;
        float4 hv = *(const float4*)(hr + c);
        float4 ov = *(const float4*)(th + c);
        ov.x += cmb * hv.x; ov.y += cmb * hv.y;
        ov.z += cmb * hv.z; ov.w += cmb * hv.w;
        *(float4*)(th + c) = ov;
    }
}

extern "C" void kernel_launch(void* const* d_in, const int* in_sizes, int n_in,
                              void* d_out, int out_size, void* d_ws, size_t ws_size,
                              hipStream_t stream) {
    const float* inputs = (const float*)d_in[0];
    const float* hidden = (const float*)d_in[1];
    const float* W_ih   = (const float*)d_in[2];
    const float* b_ih   = (const float*)d_in[3];
    const float* W_hh   = (const float*)d_in[4];
    const float* b_hh   = (const float*)d_in[5];
    const float* W_halt = (const float*)d_in[6];
    const float* b_halt = (const float*)d_in[7];
    float* out = (float*)d_out;

    float* ws = (float*)d_ws;
    const size_t NM = (size_t)BATCH * HID;               // 4M
    float* xbase = ws;                                   // 4M f32
    float* h     = xbase + NM;                           // 4M f32
    _Float16* B3ih = (_Float16*)(h + NM);                // 1024*3072 halfs
    _Float16* B3hh = B3ih + (size_t)HID * KV;
    _Float16* Ahi0 = B3hh + (size_t)HID * KV;            // 4M halfs each
    _Float16* Alo0 = Ahi0 + NM;
    _Float16* Ahi1 = Alo0 + NM;
    _Float16* Alo1 = Ahi1 + NM;
    float* flagcol = (float*)(Alo1 + NM);                // 1024
    float* halt_accum = flagcol + KDIM;                  // 4096
    float* tot_rem = halt_accum + BATCH;                 // 4096
    int* list0 = (int*)(tot_rem + BATCH);                // 4096
    int* list1 = list0 + BATCH;                          // 4096
    int* counts = list1 + BATCH;                         // 16

    _Float16* Ahi[2] = {Ahi0, Ahi1};
    _Float16* Alo[2] = {Alo0, Alo1};
    int* lists[2] = {list0, list1};

    float* tot_h = out;
    float* ponder = out + NM;
    float* steps_out = ponder + 1;

    // setup + split fused: inputs -> buf1 (dead after x_base), hidden -> buf0
    setup_kernel<<<16384, 256, 0, stream>>>(W_ih, W_hh, inputs, hidden,
                                            B3ih, B3hh, Ahi1, Alo1, Ahi0, Alo0,
                                            flagcol, list0, counts, halt_accum, tot_rem);

    // x_base = inputs @ W_ih[:, :-1].T + b_ih
    mfma_step_kernel<<<1024, 64, 0, stream>>>(
        Ahi1, Alo1, B3ih, b_ih, nullptr, nullptr, 0.f, nullptr, nullptr,
        nullptr, nullptr, nullptr, xbase, 0);

    for (int t = 0; t < NSTEP; t++) {
        mfma_step_kernel<<<1024, 64, 0, stream>>>(
            Ahi[t & 1], Alo[t & 1], B3hh, b_hh, xbase, flagcol,
            (t == 0) ? 1.f : 0.f, lists[t & 1], counts + t,
            h, Ahi[(t + 1) & 1], Alo[(t + 1) & 1], nullptr, 1);
        halt_kernel<<<1024, 256, 0, stream>>>(h, W_halt, b_halt,
                                              lists[t & 1], counts + t,
                                              lists[(t + 1) & 1], counts + t + 1,
                                              halt_accum, tot_rem, tot_h, steps_out,
                                              t + 1, (t == 0) ? 1 : 0);
    }
    epilogue_kernel<<<1025, 256, 0, stream>>>(h, lists[1], counts + 15,
                                              halt_accum, tot_rem, tot_h, steps_out, ponder);
}